// Round 4
// baseline (204.061 us; speedup 1.0000x reference)
//
#include <hip/hip_runtime.h>
#include <math.h>

#define NBLOCKS 2048

// ws layout:
//   float  coef[40]           @ offset 0    (mu_post[16], S00[8], 2*S01[8], S11[8])
//   double partials[NBLOCKS]  @ offset 512

__global__ void setup_kernel(const float* __restrict__ mu_like,
                             const float* __restrict__ pose,
                             const float* __restrict__ sp_prior,
                             const float* __restrict__ sp_like,
                             float* __restrict__ coef)
{
    if (blockIdx.x != 0 || threadIdx.x != 0) return;

    double cx = 0.0, cy = 0.0;
    for (int i = 0; i < 8; ++i) { cx += (double)mu_like[2*i]; cy += (double)mu_like[2*i+1]; }
    cx *= 0.125; cy *= 0.125;
    double th = (double)pose[2], ct = cos(th), st = sin(th);
    double tx = (double)pose[0], ty = (double)pose[1];

    for (int n = 0; n < 8; ++n) {
        double px = (double)mu_like[2*n]   - cx;
        double py = (double)mu_like[2*n+1] - cy;
        double mp0 = ct*px - st*py + tx;
        double mp1 = st*px + ct*py + ty;

        const float* p = sp_prior + 4*n;
        double s00 = (double)p[0]*p[0] + (double)p[1]*p[1] + 1e-6;
        double s01 = (double)p[0]*p[2] + (double)p[1]*p[3];
        double s11 = (double)p[2]*p[2] + (double)p[3]*p[3] + 1e-6;
        double det = s00*s11 - s01*s01;
        double Pp00 = s11/det, Pp01 = -s01/det, Pp11 = s00/det;

        const float* l = sp_like + 4*n;
        double t00 = (double)l[0]*l[0] + (double)l[1]*l[1] + 1e-6;
        double t01 = (double)l[0]*l[2] + (double)l[1]*l[3];
        double t11 = (double)l[2]*l[2] + (double)l[3]*l[3] + 1e-6;
        double dl = t00*t11 - t01*t01;
        double Pl00 = t11/dl, Pl01 = -t01/dl, Pl11 = t00/dl;

        double Q00 = Pp00 + Pl00, Q01 = Pp01 + Pl01, Q11 = Pp11 + Pl11;
        double dq = Q00*Q11 - Q01*Q01;
        double S00 = Q11/dq, S01 = -Q01/dq, S11v = Q00/dq;

        double ml0 = (double)mu_like[2*n], ml1 = (double)mu_like[2*n+1];
        double v0 = Pp00*mp0 + Pp01*mp1 + Pl00*ml0 + Pl01*ml1;
        double v1 = Pp01*mp0 + Pp11*mp1 + Pl01*ml0 + Pl11*ml1;
        coef[2*n]   = (float)(S00*v0 + S01*v1);
        coef[2*n+1] = (float)(S01*v0 + S11v*v1);
        coef[16+n]  = (float)S00;
        coef[24+n]  = (float)(2.0*S01);
        coef[32+n]  = (float)S11v;
    }
}

__global__ __launch_bounds__(256) void quad_stream_kernel(
    const float4* __restrict__ obs4,
    const float*  __restrict__ coef,
    double*       __restrict__ partials,
    int n4)
{
    const int tid    = blockIdx.x * blockDim.x + threadIdx.x;
    const int stride = gridDim.x * blockDim.x;   // multiple of 4 -> q loop-invariant
    const int q = tid & 3;

    const float m0 = coef[4*q+0], m1 = coef[4*q+1];
    const float m2 = coef[4*q+2], m3 = coef[4*q+3];
    const float a0 = coef[16+2*q],   b0 = coef[24+2*q],   c0 = coef[32+2*q];
    const float a1 = coef[16+2*q+1], b1 = coef[24+2*q+1], c1 = coef[32+2*q+1];

    float acc0 = 0.f, acc1 = 0.f;   // two independent fp32 accumulators
    int i = tid;

    // main: batches of 8 independent loads, no cross-batch dependency
    while (i + 7*stride < n4) {
        float4 v[8];
        #pragma unroll
        for (int j = 0; j < 8; ++j) v[j] = obs4[i + j*stride];
        #pragma unroll
        for (int j = 0; j < 8; ++j) {
            float d0 = v[j].x - m0, d1 = v[j].y - m1;
            float d2 = v[j].z - m2, d3 = v[j].w - m3;
            float t = a0*d0*d0 + b0*(d0*d1) + c0*d1*d1
                    + a1*d2*d2 + b1*(d2*d3) + c1*d3*d3;
            if (j & 1) acc1 += t; else acc0 += t;
        }
        i += 8*stride;
    }
    for (; i < n4; i += stride) {   // tail (empty for exact 16-iter case)
        float4 v = obs4[i];
        float d0 = v.x - m0, d1 = v.y - m1;
        float d2 = v.z - m2, d3 = v.w - m3;
        acc0 += a0*d0*d0 + b0*(d0*d1) + c0*d1*d1
              + a1*d2*d2 + b1*(d2*d3) + c1*d3*d3;
    }

    double accd = (double)acc0 + (double)acc1;

    #pragma unroll
    for (int off = 32; off > 0; off >>= 1)
        accd += __shfl_down(accd, off, 64);

    __shared__ double lds[4];
    const int wave = threadIdx.x >> 6;
    if ((threadIdx.x & 63) == 0) lds[wave] = accd;
    __syncthreads();
    if (threadIdx.x == 0)
        partials[blockIdx.x] = lds[0] + lds[1] + lds[2] + lds[3];
}

__global__ __launch_bounds__(256) void finalize_kernel(
    const double* __restrict__ partials,
    const float*  __restrict__ sp_prior,
    const float*  __restrict__ sp_like,
    float*        __restrict__ out,
    int nblocks, double n_obs)
{
    double s = 0.0;
    for (int i = threadIdx.x; i < nblocks; i += 256) s += partials[i];
    #pragma unroll
    for (int off = 32; off > 0; off >>= 1)
        s += __shfl_down(s, off, 64);
    __shared__ double lds[4];
    const int wave = threadIdx.x >> 6;
    if ((threadIdx.x & 63) == 0) lds[wave] = s;
    __syncthreads();

    if (threadIdx.x == 0) {
        double total = lds[0] + lds[1] + lds[2] + lds[3];
        double logdet = 0.0;
        for (int n = 0; n < 8; ++n) {
            const float* p = sp_prior + 4*n;
            double s00 = (double)p[0]*p[0] + (double)p[1]*p[1] + 1e-6;
            double s01 = (double)p[0]*p[2] + (double)p[1]*p[3];
            double s11 = (double)p[2]*p[2] + (double)p[3]*p[3] + 1e-6;
            double det = s00*s11 - s01*s01;
            double Pp00 = s11/det, Pp01 = -s01/det, Pp11 = s00/det;
            const float* l = sp_like + 4*n;
            double t00 = (double)l[0]*l[0] + (double)l[1]*l[1] + 1e-6;
            double t01 = (double)l[0]*l[2] + (double)l[1]*l[3];
            double t11 = (double)l[2]*l[2] + (double)l[3]*l[3] + 1e-6;
            double dl = t00*t11 - t01*t01;
            double Pl00 = t11/dl, Pl01 = -t01/dl, Pl11 = t00/dl;
            double Q00 = Pp00 + Pl00, Q01 = Pp01 + Pl01, Q11 = Pp11 + Pl11;
            logdet += log(Q00*Q11 - Q01*Q01);
        }
        const double LOG_2PI = 1.8378770664093454835606594728112;
        double c = n_obs * (16.0 * LOG_2PI + 0.5 * logdet);
        out[0] = (float)(c + 0.5 * total);
    }
}

extern "C" void kernel_launch(void* const* d_in, const int* in_sizes, int n_in,
                              void* d_out, int out_size, void* d_ws, size_t ws_size,
                              hipStream_t stream) {
    const float* obs      = (const float*)d_in[0];
    const float* mu_like  = (const float*)d_in[1];
    const float* pose     = (const float*)d_in[2];
    const float* sp_prior = (const float*)d_in[3];
    const float* sp_like  = (const float*)d_in[4];
    float* out = (float*)d_out;

    float*  coef     = (float*)d_ws;
    double* partials = (double*)((char*)d_ws + 512);

    const int n_elems  = in_sizes[0];        // 32,000,000
    const int n4       = n_elems / 4;        // 8,388,608 float4s
    const double n_obs = (double)(n_elems / 16);

    setup_kernel<<<1, 64, 0, stream>>>(mu_like, pose, sp_prior, sp_like, coef);

    quad_stream_kernel<<<NBLOCKS, 256, 0, stream>>>(
        (const float4*)obs, coef, partials, n4);

    finalize_kernel<<<1, 256, 0, stream>>>(partials, sp_prior, sp_like, out, NBLOCKS, n_obs);
}

// Round 6
// 192.186 us; speedup vs baseline: 1.0618x; 1.0618x over previous
//
#include <hip/hip_runtime.h>
#include <math.h>

#define EPS_COV 1e-6f
#define NBLOCKS 2048

typedef float vfloat4 __attribute__((ext_vector_type(4)));  // nt-load-compatible

// ws layout: double partials[NBLOCKS] @ offset 0 (plain stores, reduced by finalize).

__global__ __launch_bounds__(256) void quad_stream_kernel(
    const vfloat4* __restrict__ obs4,
    const float*  __restrict__ mu_like,
    const float*  __restrict__ pose,
    const float*  __restrict__ sp_prior,
    const float*  __restrict__ sp_like,
    double*       __restrict__ partials,
    int n4)
{
    const int tid    = blockIdx.x * blockDim.x + threadIdx.x;
    const int stride = gridDim.x * blockDim.x;   // multiple of 4 -> q loop-invariant
    const int q = tid & 3;                       // which float4-quarter of the row

    // ---- wave-uniform fp32 setup (once per thread; negligible vs stream) ----
    float cx = 0.f, cy = 0.f;
    #pragma unroll
    for (int i = 0; i < 8; ++i) { cx += mu_like[2*i]; cy += mu_like[2*i+1]; }
    cx *= 0.125f; cy *= 0.125f;
    const float ct = cosf(pose[2]), st = sinf(pose[2]);
    const float tx = pose[0], ty = pose[1];

    float m0=0.f, m1=0.f, m2=0.f, m3=0.f;
    float a0=0.f, b0=0.f, c0=0.f, a1=0.f, b1=0.f, c1=0.f;

    #pragma unroll
    for (int n = 0; n < 8; ++n) {
        float px = mu_like[2*n]   - cx;
        float py = mu_like[2*n+1] - cy;
        float mp0 = ct*px - st*py + tx;
        float mp1 = st*px + ct*py + ty;

        const float* p = sp_prior + 4*n;
        float s00 = p[0]*p[0] + p[1]*p[1] + EPS_COV;
        float s01 = p[0]*p[2] + p[1]*p[3];
        float s11 = p[2]*p[2] + p[3]*p[3] + EPS_COV;
        float det = s00*s11 - s01*s01;
        float Pp00 =  s11/det, Pp01 = -s01/det, Pp11 = s00/det;

        const float* l = sp_like + 4*n;
        float t00 = l[0]*l[0] + l[1]*l[1] + EPS_COV;
        float t01 = l[0]*l[2] + l[1]*l[3];
        float t11 = l[2]*l[2] + l[3]*l[3] + EPS_COV;
        float dl = t00*t11 - t01*t01;
        float Pl00 =  t11/dl, Pl01 = -t01/dl, Pl11 = t00/dl;

        float Q00 = Pp00 + Pl00, Q01 = Pp01 + Pl01, Q11 = Pp11 + Pl11;
        float dq = Q00*Q11 - Q01*Q01;
        float S00 = Q11/dq, S01 = -Q01/dq, S11v = Q00/dq;

        float ml0 = mu_like[2*n], ml1 = mu_like[2*n+1];
        float v0 = Pp00*mp0 + Pp01*mp1 + Pl00*ml0 + Pl01*ml1;
        float v1 = Pp01*mp0 + Pp11*mp1 + Pl01*ml0 + Pl11*ml1;
        float mpostx = S00*v0 + S01*v1;
        float mposty = S01*v0 + S11v*v1;

        if (n == 2*q)     { m0 = mpostx; m1 = mposty; a0 = S00; b0 = 2.f*S01; c0 = S11v; }
        if (n == 2*q + 1) { m2 = mpostx; m3 = mposty; a1 = S00; b1 = 2.f*S01; c1 = S11v; }
    }

    // ---- streaming quad-form accumulation, NON-TEMPORAL loads ----
    float acc0 = 0.f, acc1 = 0.f;
    int i = tid;
    while (i + 7*stride < n4) {
        vfloat4 v[8];
        #pragma unroll
        for (int j = 0; j < 8; ++j)
            v[j] = __builtin_nontemporal_load(&obs4[i + j*stride]);
        #pragma unroll
        for (int j = 0; j < 8; ++j) {
            float d0 = v[j].x - m0, d1 = v[j].y - m1;
            float d2 = v[j].z - m2, d3 = v[j].w - m3;
            float t = a0*d0*d0 + b0*(d0*d1) + c0*d1*d1
                    + a1*d2*d2 + b1*(d2*d3) + c1*d3*d3;
            if (j & 1) acc1 += t; else acc0 += t;
        }
        i += 8*stride;
    }
    for (; i < n4; i += stride) {
        vfloat4 v = __builtin_nontemporal_load(&obs4[i]);
        float d0 = v.x - m0, d1 = v.y - m1;
        float d2 = v.z - m2, d3 = v.w - m3;
        acc0 += a0*d0*d0 + b0*(d0*d1) + c0*d1*d1
              + a1*d2*d2 + b1*(d2*d3) + c1*d3*d3;
    }

    double accd = (double)acc0 + (double)acc1;

    #pragma unroll
    for (int off = 32; off > 0; off >>= 1)
        accd += __shfl_down(accd, off, 64);

    __shared__ double lds[4];
    const int wave = threadIdx.x >> 6;
    if ((threadIdx.x & 63) == 0) lds[wave] = accd;
    __syncthreads();
    if (threadIdx.x == 0)
        partials[blockIdx.x] = lds[0] + lds[1] + lds[2] + lds[3];
}

__global__ __launch_bounds__(256) void finalize_kernel(
    const double* __restrict__ partials,
    const float*  __restrict__ sp_prior,
    const float*  __restrict__ sp_like,
    float*        __restrict__ out,
    int nblocks, double n_obs)
{
    double s = 0.0;
    for (int i = threadIdx.x; i < nblocks; i += 256) s += partials[i];
    #pragma unroll
    for (int off = 32; off > 0; off >>= 1)
        s += __shfl_down(s, off, 64);
    __shared__ double lds[4];
    const int wave = threadIdx.x >> 6;
    if ((threadIdx.x & 63) == 0) lds[wave] = s;
    __syncthreads();

    if (threadIdx.x == 0) {
        double total = lds[0] + lds[1] + lds[2] + lds[3];
        double logdet = 0.0;
        for (int n = 0; n < 8; ++n) {
            const float* p = sp_prior + 4*n;
            double s00 = (double)p[0]*p[0] + (double)p[1]*p[1] + 1e-6;
            double s01 = (double)p[0]*p[2] + (double)p[1]*p[3];
            double s11 = (double)p[2]*p[2] + (double)p[3]*p[3] + 1e-6;
            double det = s00*s11 - s01*s01;
            double Pp00 = s11/det, Pp01 = -s01/det, Pp11 = s00/det;
            const float* l = sp_like + 4*n;
            double t00 = (double)l[0]*l[0] + (double)l[1]*l[1] + 1e-6;
            double t01 = (double)l[0]*l[2] + (double)l[1]*l[3];
            double t11 = (double)l[2]*l[2] + (double)l[3]*l[3] + 1e-6;
            double dl = t00*t11 - t01*t01;
            double Pl00 = t11/dl, Pl01 = -t01/dl, Pl11 = t00/dl;
            double Q00 = Pp00 + Pl00, Q01 = Pp01 + Pl01, Q11 = Pp11 + Pl11;
            logdet += log(Q00*Q11 - Q01*Q01);
        }
        const double LOG_2PI = 1.8378770664093454835606594728112;
        double c = n_obs * (16.0 * LOG_2PI + 0.5 * logdet);
        out[0] = (float)(c + 0.5 * total);
    }
}

extern "C" void kernel_launch(void* const* d_in, const int* in_sizes, int n_in,
                              void* d_out, int out_size, void* d_ws, size_t ws_size,
                              hipStream_t stream) {
    const float* obs      = (const float*)d_in[0];
    const float* mu_like  = (const float*)d_in[1];
    const float* pose     = (const float*)d_in[2];
    const float* sp_prior = (const float*)d_in[3];
    const float* sp_like  = (const float*)d_in[4];
    float* out = (float*)d_out;

    double* partials = (double*)d_ws;

    const int n_elems  = in_sizes[0];        // 32,000,000
    const int n4       = n_elems / 4;        // 8,388,608 float4s
    const double n_obs = (double)(n_elems / 16);

    quad_stream_kernel<<<NBLOCKS, 256, 0, stream>>>(
        (const vfloat4*)obs, mu_like, pose, sp_prior, sp_like, partials, n4);

    finalize_kernel<<<1, 256, 0, stream>>>(partials, sp_prior, sp_like, out, NBLOCKS, n_obs);
}